// Round 2
// baseline (183.446 us; speedup 1.0000x reference)
//
#include <hip/hip_runtime.h>

static constexpr int Vn = 1024;   // codebook size
static constexpr int Dn = 256;    // code dim
static constexpr int NT = 65536;  // B * TOK

// ---------------------------------------------------------------------------
// Kernel 1: G = W * W^T (1024x1024, K=256), fp32, 32x32 tiles, 1024 blocks
// (4 blocks/CU vs round-1's 1 block/CU). Fuses norms[v] = G[v][v] extraction.
// FLOP floor is 3.4 us at 157 TF vector fp32; this should land ~4-5 us.
// ---------------------------------------------------------------------------
__global__ __launch_bounds__(256) void gram_kernel(const float* __restrict__ W,
                                                   float* __restrict__ G,
                                                   float* __restrict__ norms) {
    __shared__ float As[32][33];  // [k][m], +1 pad
    __shared__ float Bs[32][33];
    const int tid = threadIdx.x;
    const int tx = tid & 15;   // 0..15
    const int ty = tid >> 4;   // 0..15
    const int bm = blockIdx.y * 32;
    const int bn = blockIdx.x * 32;
    float acc[2][2] = {};
    for (int k0 = 0; k0 < Dn; k0 += 32) {
#pragma unroll
        for (int s = 0; s < 4; ++s) {
            const int e = tid + 256 * s;
            const int m = e >> 5;   // 0..31
            const int k = e & 31;   // 0..31 -> 128B coalesced per 32 lanes
            As[k][m] = W[(bm + m) * Dn + k0 + k];
            Bs[k][m] = W[(bn + m) * Dn + k0 + k];
        }
        __syncthreads();
#pragma unroll
        for (int kk = 0; kk < 32; ++kk) {
            float a[2], b[2];
#pragma unroll
            for (int u = 0; u < 2; ++u) a[u] = As[kk][ty + 16 * u];
#pragma unroll
            for (int w = 0; w < 2; ++w) b[w] = Bs[kk][tx + 16 * w];
#pragma unroll
            for (int u = 0; u < 2; ++u)
#pragma unroll
                for (int w = 0; w < 2; ++w)
                    acc[u][w] = fmaf(a[u], b[w], acc[u][w]);
        }
        __syncthreads();
    }
#pragma unroll
    for (int u = 0; u < 2; ++u) {
        const int row = bm + ty + 16 * u;
#pragma unroll
        for (int w = 0; w < 2; ++w) {
            const int col = bn + tx + 16 * w;
            G[row * Vn + col] = acc[u][w];
            if (row == col) norms[row] = acc[u][w];  // fused diag
        }
    }
}

// ---------------------------------------------------------------------------
// Counting sort of tokens by seq[t] (1024 buckets, ~64 tokens each).
// ---------------------------------------------------------------------------
__global__ void hist_kernel(const int* __restrict__ seq, int* __restrict__ counts) {
    const int t = blockIdx.x * 256 + threadIdx.x;
    atomicAdd(&counts[seq[t]], 1);
}

__global__ __launch_bounds__(1024) void scan_kernel(const int* __restrict__ counts,
                                                    int* __restrict__ base,
                                                    int* __restrict__ cursor) {
    __shared__ int sc[1024];
    const int tid = threadIdx.x;
    const int c = counts[tid];
    sc[tid] = c;
    __syncthreads();
    for (int off = 1; off < 1024; off <<= 1) {
        int v = sc[tid];
        if (tid >= off) v += sc[tid - off];
        __syncthreads();
        sc[tid] = v;
        __syncthreads();
    }
    const int b = sc[tid] - c;  // exclusive
    base[tid] = b;
    cursor[tid] = b;
    if (tid == 1023) base[1024] = sc[1023];  // sentinel = NT
}

__global__ void scatter_kernel(const int* __restrict__ seq, int* __restrict__ cursor,
                               int* __restrict__ sorted) {
    const int t = blockIdx.x * 256 + threadIdx.x;
    const int p = atomicAdd(&cursor[seq[t]], 1);
    sorted[p] = t;
}

// ---------------------------------------------------------------------------
// Kernel: per-token argmin, bucketed by i. Block bi handles all tokens with
// seq[t] == bi: stages s[v] = norms[v] + c0*G[bi,v] in LDS once, then each
// wave streams only G[j,:] (4 KB/token instead of 8 KB -> L2 traffic halved).
// fmaf order identical to round 1 (bit-identical scores -> same argmin).
// ---------------------------------------------------------------------------
__global__ __launch_bounds__(256) void argmin_kernel(const int* __restrict__ seq2,
                                                     const float* __restrict__ alpha,
                                                     const float* __restrict__ G,
                                                     const float* __restrict__ norms,
                                                     const int* __restrict__ base,
                                                     const int* __restrict__ sorted,
                                                     int* __restrict__ out_idx) {
    __shared__ float s[Vn];
    const int i = blockIdx.x;
    const int tid = threadIdx.x;
    const float a = alpha[0];
    const float c0 = -2.0f * (1.0f - a);
    const float c1 = -2.0f * a;
    {   // stage s[v] = fmaf(c0, G[i,v], norms[v])
        const float4 g = ((const float4*)(G + i * Vn))[tid];
        const float4 n = ((const float4*)norms)[tid];
        float4 r;
        r.x = fmaf(c0, g.x, n.x);
        r.y = fmaf(c0, g.y, n.y);
        r.z = fmaf(c0, g.z, n.z);
        r.w = fmaf(c0, g.w, n.w);
        ((float4*)s)[tid] = r;
    }
    __syncthreads();
    const int start = base[i];
    const int end = base[i + 1];
    const int wave = tid >> 6;
    const int lane = tid & 63;
    const float4* s4 = (const float4*)s;
    for (int p = start + wave; p < end; p += 4) {
        const int t = sorted[p];
        const int j = seq2[t];
        const float4* Gj = (const float4*)(G + j * Vn);
        float best = __builtin_inff();
        int bestV = 0;
#pragma unroll
        for (int q = 0; q < 4; ++q) {
            const int e = q * 64 + lane;  // v = 4e..4e+3 ascending per lane
            const float4 gj = Gj[e];
            const float4 ss = s4[e];
            const float sc0 = fmaf(c1, gj.x, ss.x);
            const float sc1 = fmaf(c1, gj.y, ss.y);
            const float sc2 = fmaf(c1, gj.z, ss.z);
            const float sc3 = fmaf(c1, gj.w, ss.w);
            const int v = e * 4;
            if (sc0 < best) { best = sc0; bestV = v; }
            if (sc1 < best) { best = sc1; bestV = v + 1; }
            if (sc2 < best) { best = sc2; bestV = v + 2; }
            if (sc3 < best) { best = sc3; bestV = v + 3; }
        }
        // 64-lane reduce, lexicographic (score, v) = jnp.argmin first-min tie-break
#pragma unroll
        for (int off = 32; off >= 1; off >>= 1) {
            const float ob = __shfl_down(best, off, 64);
            const int   ov = __shfl_down(bestV, off, 64);
            if (ob < best || (ob == best && ov < bestV)) { best = ob; bestV = ov; }
        }
        if (lane == 0) out_idx[t] = bestV;
    }
}

// ---------------------------------------------------------------------------
// Kernel: out[b, d, h, w] = W[idx[b*256 + h*16 + w], d] via 32x33 LDS transpose.
// ---------------------------------------------------------------------------
__global__ __launch_bounds__(256) void gather_transpose_kernel(const float* __restrict__ W,
                                                               const int* __restrict__ idx,
                                                               float* __restrict__ out) {
    __shared__ float tile[32][33];
    const int b   = blockIdx.z;
    const int hw0 = blockIdx.x * 32;
    const int d0  = blockIdx.y * 32;
    const int tx  = threadIdx.x & 31;
    const int ty  = threadIdx.x >> 5;  // 0..7
#pragma unroll
    for (int r = ty; r < 32; r += 8) {
        const int row = idx[b * 256 + hw0 + r];
        tile[r][tx] = W[row * Dn + d0 + tx];
    }
    __syncthreads();
#pragma unroll
    for (int r = ty; r < 32; r += 8) {
        out[b * 65536 + (d0 + r) * 256 + hw0 + tx] = tile[tx][r];
    }
}

// ---------------------------------------------------------------------------
extern "C" void kernel_launch(void* const* d_in, const int* in_sizes, int n_in,
                              void* d_out, int out_size, void* d_ws, size_t ws_size,
                              hipStream_t stream) {
    const int*   seq   = (const int*)d_in[0];    // [256,256] int32
    const int*   seq2  = (const int*)d_in[1];    // [256,256] int32
    const float* alpha = (const float*)d_in[2];  // [1]
    const float* W     = (const float*)d_in[3];  // [1024,256] f32
    float* out = (float*)d_out;                  // [256,256,16,16] f32

    char* ws = (char*)d_ws;
    float* G      = (float*)(ws);                       // 4 MB
    float* norms  = (float*)(ws + 4194304);             // 4 KB
    int*   idx    = (int*)  (ws + 4198400);             // 256 KB
    int*   counts = (int*)  (ws + 4460544);             // 4 KB
    int*   base   = (int*)  (ws + 4464640);             // 4 KB + 8 (1025 ints)
    int*   cursor = (int*)  (ws + 4468752);             // 4 KB
    int*   sorted = (int*)  (ws + 4472848);             // 256 KB

    gram_kernel<<<dim3(32, 32), 256, 0, stream>>>(W, G, norms);
    hipMemsetAsync(counts, 0, Vn * sizeof(int), stream);
    hist_kernel<<<NT / 256, 256, 0, stream>>>(seq, counts);
    scan_kernel<<<1, 1024, 0, stream>>>(counts, base, cursor);
    scatter_kernel<<<NT / 256, 256, 0, stream>>>(seq, cursor, sorted);
    argmin_kernel<<<Vn, 256, 0, stream>>>(seq2, alpha, G, norms, base, sorted, idx);
    gather_transpose_kernel<<<dim3(8, 8, 256), 256, 0, stream>>>(W, idx, out);
}

// Round 3
// 142.917 us; speedup vs baseline: 1.2836x; 1.2836x over previous
//
#include <hip/hip_runtime.h>

static constexpr int Vn = 1024;   // codebook size
static constexpr int Dn = 256;    // code dim
static constexpr int NT = 65536;  // B * TOK

// ---------------------------------------------------------------------------
// Kernel 1: G = W * W^T (1024x1024, K=256), fp32, 32x32 tiles, 1024 blocks
// (4 blocks/CU). Fuses norms[v] = G[v][v]. fp32 exact -> argmin margins safe.
// ---------------------------------------------------------------------------
__global__ __launch_bounds__(256) void gram_kernel(const float* __restrict__ W,
                                                   float* __restrict__ G,
                                                   float* __restrict__ norms) {
    __shared__ float As[32][33];  // [k][m], +1 pad
    __shared__ float Bs[32][33];
    const int tid = threadIdx.x;
    const int tx = tid & 15;   // 0..15
    const int ty = tid >> 4;   // 0..15
    const int bm = blockIdx.y * 32;
    const int bn = blockIdx.x * 32;
    float acc[2][2] = {};
    for (int k0 = 0; k0 < Dn; k0 += 32) {
#pragma unroll
        for (int s = 0; s < 4; ++s) {
            const int e = tid + 256 * s;
            const int m = e >> 5;   // 0..31
            const int k = e & 31;   // 128B coalesced per 32 lanes
            As[k][m] = W[(bm + m) * Dn + k0 + k];
            Bs[k][m] = W[(bn + m) * Dn + k0 + k];
        }
        __syncthreads();
#pragma unroll
        for (int kk = 0; kk < 32; ++kk) {
            float a[2], b[2];
#pragma unroll
            for (int u = 0; u < 2; ++u) a[u] = As[kk][ty + 16 * u];
#pragma unroll
            for (int w = 0; w < 2; ++w) b[w] = Bs[kk][tx + 16 * w];
#pragma unroll
            for (int u = 0; u < 2; ++u)
#pragma unroll
                for (int w = 0; w < 2; ++w)
                    acc[u][w] = fmaf(a[u], b[w], acc[u][w]);
        }
        __syncthreads();
    }
#pragma unroll
    for (int u = 0; u < 2; ++u) {
        const int row = bm + ty + 16 * u;
#pragma unroll
        for (int w = 0; w < 2; ++w) {
            const int col = bn + tx + 16 * w;
            G[row * Vn + col] = acc[u][w];
            if (row == col) norms[row] = acc[u][w];  // fused diag
        }
    }
}

// ---------------------------------------------------------------------------
// Kernel 2: per-token argmin over V codes.
//   score(v) = norms[v] - 2(1-a) G[i,v] - 2a G[j,v]
// 16 tokens/block (4/wave). All 8 token indices prefetched upfront; G-row
// loads for 2 tokens (16 float4) issued as one batch -> 2x loads in flight
// vs round 1, half the exposed latency chains. fmaf order identical to
// round 1 -> bit-identical scores -> same argmin (absmax 0.0).
// ---------------------------------------------------------------------------
__global__ __launch_bounds__(256) void argmin_kernel(const int* __restrict__ seq,
                                                     const int* __restrict__ seq2,
                                                     const float* __restrict__ alpha,
                                                     const float* __restrict__ G,
                                                     const float* __restrict__ norms,
                                                     int* __restrict__ out_idx) {
    __shared__ float nrm[Vn];
    const int tid = threadIdx.x;
    {   // stage norms: 256 threads x 16 B = 4 KB
        ((float4*)nrm)[tid] = ((const float4*)norms)[tid];
    }
    __syncthreads();
    const float a = alpha[0];
    const float c0 = -2.0f * (1.0f - a);
    const float c1 = -2.0f * a;
    const int wave = tid >> 6;
    const int lane = tid & 63;
    const int base_t = blockIdx.x * 16 + wave * 4;
    const float4* nr = (const float4*)nrm;
    // prefetch all 8 indices (independent loads, small & L2-hot)
    int iv[4], jv[4];
#pragma unroll
    for (int q = 0; q < 4; ++q) { iv[q] = seq[base_t + q]; jv[q] = seq2[base_t + q]; }
#pragma unroll
    for (int pair = 0; pair < 2; ++pair) {
        const int qa = pair * 2, qb = pair * 2 + 1;
        const float4* GiA = (const float4*)(G + iv[qa] * Vn);
        const float4* GjA = (const float4*)(G + jv[qa] * Vn);
        const float4* GiB = (const float4*)(G + iv[qb] * Vn);
        const float4* GjB = (const float4*)(G + jv[qb] * Vn);
        // issue all 16 float4 loads for two tokens before any consumption
        float4 gia[4], gja[4], gib[4], gjb[4];
#pragma unroll
        for (int s = 0; s < 4; ++s) {
            const int e = s * 64 + lane;
            gia[s] = GiA[e];
            gja[s] = GjA[e];
            gib[s] = GiB[e];
            gjb[s] = GjB[e];
        }
        float bestA = __builtin_inff(), bestB = __builtin_inff();
        int vA = 0, vB = 0;
#pragma unroll
        for (int s = 0; s < 4; ++s) {
            const int e = s * 64 + lane;  // v = 4e..4e+3 ascending per lane
            const float4 nn = nr[e];
            const int v = e * 4;
            {
                const float s0 = fmaf(c1, gja[s].x, fmaf(c0, gia[s].x, nn.x));
                const float s1 = fmaf(c1, gja[s].y, fmaf(c0, gia[s].y, nn.y));
                const float s2 = fmaf(c1, gja[s].z, fmaf(c0, gia[s].z, nn.z));
                const float s3 = fmaf(c1, gja[s].w, fmaf(c0, gia[s].w, nn.w));
                if (s0 < bestA) { bestA = s0; vA = v; }
                if (s1 < bestA) { bestA = s1; vA = v + 1; }
                if (s2 < bestA) { bestA = s2; vA = v + 2; }
                if (s3 < bestA) { bestA = s3; vA = v + 3; }
            }
            {
                const float s0 = fmaf(c1, gjb[s].x, fmaf(c0, gib[s].x, nn.x));
                const float s1 = fmaf(c1, gjb[s].y, fmaf(c0, gib[s].y, nn.y));
                const float s2 = fmaf(c1, gjb[s].z, fmaf(c0, gib[s].z, nn.z));
                const float s3 = fmaf(c1, gjb[s].w, fmaf(c0, gib[s].w, nn.w));
                if (s0 < bestB) { bestB = s0; vB = v; }
                if (s1 < bestB) { bestB = s1; vB = v + 1; }
                if (s2 < bestB) { bestB = s2; vB = v + 2; }
                if (s3 < bestB) { bestB = s3; vB = v + 3; }
            }
        }
        // 64-lane reduce, lexicographic (score, v) = jnp.argmin first-min
#pragma unroll
        for (int off = 32; off >= 1; off >>= 1) {
            const float oa = __shfl_down(bestA, off, 64);
            const int   va = __shfl_down(vA, off, 64);
            if (oa < bestA || (oa == bestA && va < vA)) { bestA = oa; vA = va; }
            const float ob = __shfl_down(bestB, off, 64);
            const int   vb = __shfl_down(vB, off, 64);
            if (ob < bestB || (ob == bestB && vb < vB)) { bestB = ob; vB = vb; }
        }
        if (lane == 0) {
            out_idx[base_t + qa] = vA;
            out_idx[base_t + qb] = vB;
        }
    }
}

// ---------------------------------------------------------------------------
// Kernel 3: out[b, d, h, w] = W[idx[b*256 + h*16 + w], d]
// 64x64 LDS-transpose tiles (4096 blocks vs round-1's 16384): coalesced
// 256 B reads from W rows and 256 B writes to out. +1 pad -> 2-way max
// conflict on transposed read (free on gfx950).
// ---------------------------------------------------------------------------
__global__ __launch_bounds__(256) void gather_transpose_kernel(const float* __restrict__ W,
                                                               const int* __restrict__ idx,
                                                               float* __restrict__ out) {
    __shared__ float tile[64][65];
    const int b   = blockIdx.z;
    const int hw0 = blockIdx.x * 64;
    const int d0  = blockIdx.y * 64;
    const int tx  = threadIdx.x & 63;
    const int ty  = threadIdx.x >> 6;  // 0..3
#pragma unroll
    for (int r = ty; r < 64; r += 4) {
        const int row = idx[b * 256 + hw0 + r];
        tile[r][tx] = W[row * Dn + d0 + tx];
    }
    __syncthreads();
#pragma unroll
    for (int r = ty; r < 64; r += 4) {
        out[b * 65536 + (d0 + r) * 256 + hw0 + tx] = tile[tx][r];
    }
}

// ---------------------------------------------------------------------------
extern "C" void kernel_launch(void* const* d_in, const int* in_sizes, int n_in,
                              void* d_out, int out_size, void* d_ws, size_t ws_size,
                              hipStream_t stream) {
    const int*   seq   = (const int*)d_in[0];    // [256,256] int32
    const int*   seq2  = (const int*)d_in[1];    // [256,256] int32
    const float* alpha = (const float*)d_in[2];  // [1]
    const float* W     = (const float*)d_in[3];  // [1024,256] f32
    float* out = (float*)d_out;                  // [256,256,16,16] f32

    char* ws = (char*)d_ws;
    float* G     = (float*)(ws);             // 4 MB
    float* norms = (float*)(ws + 4194304);   // 4 KB
    int*   idx   = (int*)  (ws + 4198400);   // 256 KB

    gram_kernel<<<dim3(32, 32), 256, 0, stream>>>(W, G, norms);
    argmin_kernel<<<NT / 16, 256, 0, stream>>>(seq, seq2, alpha, G, norms, idx);
    gather_transpose_kernel<<<dim3(4, 4, 256), 256, 0, stream>>>(W, idx, out);
}

// Round 4
// 136.621 us; speedup vs baseline: 1.3427x; 1.0461x over previous
//
#include <hip/hip_runtime.h>

static constexpr int Vn = 1024;   // codebook size
static constexpr int Dn = 256;    // code dim
static constexpr int NT = 65536;  // B * TOK

// ---------------------------------------------------------------------------
// Kernel 1: G = W * W^T (1024x1024, K=256), fp32, 32x32 tiles, 1024 blocks
// (4 blocks/CU). Fuses norms[v] = G[v][v]. fp32 exact -> argmin margins safe.
// (unchanged from round 3 — verified, ~7 us, not the lever this round)
// ---------------------------------------------------------------------------
__global__ __launch_bounds__(256) void gram_kernel(const float* __restrict__ W,
                                                   float* __restrict__ G,
                                                   float* __restrict__ norms) {
    __shared__ float As[32][33];  // [k][m], +1 pad
    __shared__ float Bs[32][33];
    const int tid = threadIdx.x;
    const int tx = tid & 15;   // 0..15
    const int ty = tid >> 4;   // 0..15
    const int bm = blockIdx.y * 32;
    const int bn = blockIdx.x * 32;
    float acc[2][2] = {};
    for (int k0 = 0; k0 < Dn; k0 += 32) {
#pragma unroll
        for (int s = 0; s < 4; ++s) {
            const int e = tid + 256 * s;
            const int m = e >> 5;   // 0..31
            const int k = e & 31;   // 128B coalesced per 32 lanes
            As[k][m] = W[(bm + m) * Dn + k0 + k];
            Bs[k][m] = W[(bn + m) * Dn + k0 + k];
        }
        __syncthreads();
#pragma unroll
        for (int kk = 0; kk < 32; ++kk) {
            float a[2], b[2];
#pragma unroll
            for (int u = 0; u < 2; ++u) a[u] = As[kk][ty + 16 * u];
#pragma unroll
            for (int w = 0; w < 2; ++w) b[w] = Bs[kk][tx + 16 * w];
#pragma unroll
            for (int u = 0; u < 2; ++u)
#pragma unroll
                for (int w = 0; w < 2; ++w)
                    acc[u][w] = fmaf(a[u], b[w], acc[u][w]);
        }
        __syncthreads();
    }
#pragma unroll
    for (int u = 0; u < 2; ++u) {
        const int row = bm + ty + 16 * u;
#pragma unroll
        for (int w = 0; w < 2; ++w) {
            const int col = bn + tx + 16 * w;
            G[row * Vn + col] = acc[u][w];
            if (row == col) norms[row] = acc[u][w];  // fused diag
        }
    }
}

// ---------------------------------------------------------------------------
// Kernel 2 (FUSED): per-token argmin + direct output write.
// Block owns 32 consecutive tokens (one image slice, since 32 | 256).
// Phase 1: round-3 argmin, identical fmaf order -> bit-identical indices.
//          Each wave handles 8 tokens (2 batches of 4, loads of 2 tokens
//          batched for MLP). bestV -> LDS.
// Phase 2: gather W[bestV] rows into a 32x257-padded LDS tile ([tok][d]),
//          then write out[b, d, hw0..hw0+31] as 128 B-contiguous rows with
//          NON-TEMPORAL stores (full lines; keeps G resident in L2 for the
//          argmin waves still in flight on the same XCD).
// ---------------------------------------------------------------------------
__global__ __launch_bounds__(256) void argmin_write_kernel(const int* __restrict__ seq,
                                                           const int* __restrict__ seq2,
                                                           const float* __restrict__ alpha,
                                                           const float* __restrict__ G,
                                                           const float* __restrict__ norms,
                                                           const float* __restrict__ W,
                                                           float* __restrict__ out) {
    __shared__ float nrm[Vn];
    __shared__ float T[32][257];   // [tok][d], pad -> all LDS patterns <=2-way
    __shared__ int bestVs[32];
    const int tid = threadIdx.x;
    {   // stage norms: 256 threads x 16 B = 4 KB
        ((float4*)nrm)[tid] = ((const float4*)norms)[tid];
    }
    __syncthreads();
    const float a = alpha[0];
    const float c0 = -2.0f * (1.0f - a);
    const float c1 = -2.0f * a;
    const int wave = tid >> 6;
    const int lane = tid & 63;
    const int t0 = blockIdx.x * 32;       // first token of block
    const float4* nr = (const float4*)nrm;

    // ---- Phase 1: argmin for this wave's 8 tokens --------------------------
    for (int bb = 0; bb < 2; ++bb) {
        const int base_t = t0 + wave * 8 + bb * 4;   // global token of q=0
        const int base_l = wave * 8 + bb * 4;        // block-local
        int iv[4], jv[4];
#pragma unroll
        for (int q = 0; q < 4; ++q) { iv[q] = seq[base_t + q]; jv[q] = seq2[base_t + q]; }
#pragma unroll
        for (int pair = 0; pair < 2; ++pair) {
            const int qa = pair * 2, qb = pair * 2 + 1;
            const float4* GiA = (const float4*)(G + iv[qa] * Vn);
            const float4* GjA = (const float4*)(G + jv[qa] * Vn);
            const float4* GiB = (const float4*)(G + iv[qb] * Vn);
            const float4* GjB = (const float4*)(G + jv[qb] * Vn);
            float4 gia[4], gja[4], gib[4], gjb[4];
#pragma unroll
            for (int s = 0; s < 4; ++s) {
                const int e = s * 64 + lane;
                gia[s] = GiA[e];
                gja[s] = GjA[e];
                gib[s] = GiB[e];
                gjb[s] = GjB[e];
            }
            float bestA = __builtin_inff(), bestB = __builtin_inff();
            int vA = 0, vB = 0;
#pragma unroll
            for (int s = 0; s < 4; ++s) {
                const int e = s * 64 + lane;  // v = 4e..4e+3 ascending per lane
                const float4 nn = nr[e];
                const int v = e * 4;
                {
                    const float s0 = fmaf(c1, gja[s].x, fmaf(c0, gia[s].x, nn.x));
                    const float s1 = fmaf(c1, gja[s].y, fmaf(c0, gia[s].y, nn.y));
                    const float s2 = fmaf(c1, gja[s].z, fmaf(c0, gia[s].z, nn.z));
                    const float s3 = fmaf(c1, gja[s].w, fmaf(c0, gia[s].w, nn.w));
                    if (s0 < bestA) { bestA = s0; vA = v; }
                    if (s1 < bestA) { bestA = s1; vA = v + 1; }
                    if (s2 < bestA) { bestA = s2; vA = v + 2; }
                    if (s3 < bestA) { bestA = s3; vA = v + 3; }
                }
                {
                    const float s0 = fmaf(c1, gjb[s].x, fmaf(c0, gib[s].x, nn.x));
                    const float s1 = fmaf(c1, gjb[s].y, fmaf(c0, gib[s].y, nn.y));
                    const float s2 = fmaf(c1, gjb[s].z, fmaf(c0, gib[s].z, nn.z));
                    const float s3 = fmaf(c1, gjb[s].w, fmaf(c0, gib[s].w, nn.w));
                    if (s0 < bestB) { bestB = s0; vB = v; }
                    if (s1 < bestB) { bestB = s1; vB = v + 1; }
                    if (s2 < bestB) { bestB = s2; vB = v + 2; }
                    if (s3 < bestB) { bestB = s3; vB = v + 3; }
                }
            }
            // 64-lane reduce, lexicographic (score, v) = jnp.argmin first-min
#pragma unroll
            for (int off = 32; off >= 1; off >>= 1) {
                const float oa = __shfl_down(bestA, off, 64);
                const int   va = __shfl_down(vA, off, 64);
                if (oa < bestA || (oa == bestA && va < vA)) { bestA = oa; vA = va; }
                const float ob = __shfl_down(bestB, off, 64);
                const int   vb = __shfl_down(vB, off, 64);
                if (ob < bestB || (ob == bestB && vb < vB)) { bestB = ob; vB = vb; }
            }
            if (lane == 0) {
                bestVs[base_l + qa] = vA;
                bestVs[base_l + qb] = vB;
            }
        }
    }
    __syncthreads();

    // ---- Phase 2: gather W rows into LDS tile ------------------------------
    // 16 lanes per token: 256 B contiguous global reads, 2-way-max LDS writes.
    const int l16 = tid & 15;
#pragma unroll
    for (int half = 0; half < 2; ++half) {
        const int tok = half * 16 + (tid >> 4);
        const int v = bestVs[tok];
        const float4* Wr = (const float4*)(W + v * Dn);
#pragma unroll
        for (int p = 0; p < 4; ++p) {
            const int d4 = p * 16 + l16;          // float4 index, d = 4*d4
            *(float4*)(&T[tok][d4 * 4]) = Wr[d4];
        }
    }
    __syncthreads();

    // ---- Phase 2b: transposed write-out, NT full-line stores ---------------
    const int b   = t0 >> 8;
    const int hw0 = t0 & 255;
    float* outb = out + b * 65536 + hw0;
    const int hw = tid & 31;        // 32 lanes -> 128 B contiguous per d-row
    const int dofs = tid >> 5;      // 0..7
#pragma unroll
    for (int dp = 0; dp < 256; dp += 8) {
        const int d = dp + dofs;
        __builtin_nontemporal_store(T[hw][d], outb + d * 256 + hw);
    }
}

// ---------------------------------------------------------------------------
extern "C" void kernel_launch(void* const* d_in, const int* in_sizes, int n_in,
                              void* d_out, int out_size, void* d_ws, size_t ws_size,
                              hipStream_t stream) {
    const int*   seq   = (const int*)d_in[0];    // [256,256] int32
    const int*   seq2  = (const int*)d_in[1];    // [256,256] int32
    const float* alpha = (const float*)d_in[2];  // [1]
    const float* W     = (const float*)d_in[3];  // [1024,256] f32
    float* out = (float*)d_out;                  // [256,256,16,16] f32

    char* ws = (char*)d_ws;
    float* G     = (float*)(ws);             // 4 MB
    float* norms = (float*)(ws + 4194304);   // 4 KB

    gram_kernel<<<dim3(32, 32), 256, 0, stream>>>(W, G, norms);
    argmin_write_kernel<<<NT / 32, 256, 0, stream>>>(seq, seq2, alpha, G, norms, W, out);
}

// Round 6
// 130.411 us; speedup vs baseline: 1.4067x; 1.0476x over previous
//
#include <hip/hip_runtime.h>

static constexpr int Vn = 1024;   // codebook size
static constexpr int Dn = 256;    // code dim
static constexpr int NT = 65536;  // B * TOK

typedef float vfloat4 __attribute__((ext_vector_type(4)));  // native vec for NT stores

// ---------------------------------------------------------------------------
// Kernel 1: G = W * W^T (1024x1024, K=256), fp32, 32x32 tiles, 1024 blocks
// (4 blocks/CU). Fuses norms[v] = G[v][v]. fp32 exact -> argmin margins safe.
// ---------------------------------------------------------------------------
__global__ __launch_bounds__(256) void gram_kernel(const float* __restrict__ W,
                                                   float* __restrict__ G,
                                                   float* __restrict__ norms) {
    __shared__ float As[32][33];  // [k][m], +1 pad
    __shared__ float Bs[32][33];
    const int tid = threadIdx.x;
    const int tx = tid & 15;   // 0..15
    const int ty = tid >> 4;   // 0..15
    const int bm = blockIdx.y * 32;
    const int bn = blockIdx.x * 32;
    float acc[2][2] = {};
    for (int k0 = 0; k0 < Dn; k0 += 32) {
#pragma unroll
        for (int s = 0; s < 4; ++s) {
            const int e = tid + 256 * s;
            const int m = e >> 5;   // 0..31
            const int k = e & 31;   // 128B coalesced per 32 lanes
            As[k][m] = W[(bm + m) * Dn + k0 + k];
            Bs[k][m] = W[(bn + m) * Dn + k0 + k];
        }
        __syncthreads();
#pragma unroll
        for (int kk = 0; kk < 32; ++kk) {
            float a[2], b[2];
#pragma unroll
            for (int u = 0; u < 2; ++u) a[u] = As[kk][ty + 16 * u];
#pragma unroll
            for (int w = 0; w < 2; ++w) b[w] = Bs[kk][tx + 16 * w];
#pragma unroll
            for (int u = 0; u < 2; ++u)
#pragma unroll
                for (int w = 0; w < 2; ++w)
                    acc[u][w] = fmaf(a[u], b[w], acc[u][w]);
        }
        __syncthreads();
    }
#pragma unroll
    for (int u = 0; u < 2; ++u) {
        const int row = bm + ty + 16 * u;
#pragma unroll
        for (int w = 0; w < 2; ++w) {
            const int col = bn + tx + 16 * w;
            G[row * Vn + col] = acc[u][w];
            if (row == col) norms[row] = acc[u][w];  // fused diag
        }
    }
}

// ---------------------------------------------------------------------------
// Kernel 2 (FUSED): per-token argmin + direct output write.
// Block = 32 consecutive tokens of one image. LDS = 16.6 KB (T[32][129] +
// bestVs) -> ~6 blocks/CU resident vs round-4's 4. norms live in REGISTERS
// (they depend only on (s,lane), shared across all 8 tokens of a wave).
// fmaf order identical to rounds 1-4 -> bit-identical argmin.
// ---------------------------------------------------------------------------
__global__ __launch_bounds__(256) void argmin_write_kernel(const int* __restrict__ seq,
                                                           const int* __restrict__ seq2,
                                                           const float* __restrict__ alpha,
                                                           const float* __restrict__ G,
                                                           const float* __restrict__ norms,
                                                           const float* __restrict__ W,
                                                           float* __restrict__ out) {
    __shared__ float T[32][129];   // [tok][d half], stride 129 -> <=2-way banks
    __shared__ int bestVs[32];
    const int tid = threadIdx.x;
    const int wave = tid >> 6;
    const int lane = tid & 63;
    const int t0 = blockIdx.x * 32;       // first token of block

    // norms for this lane's 16 v-slots: registers, reused by all 8 tokens
    float4 nn_r[4];
#pragma unroll
    for (int s = 0; s < 4; ++s) nn_r[s] = ((const float4*)norms)[s * 64 + lane];

    const float a = alpha[0];
    const float c0 = -2.0f * (1.0f - a);
    const float c1 = -2.0f * a;

    // ---- Phase 1: argmin for this wave's 8 tokens --------------------------
    for (int bb = 0; bb < 2; ++bb) {
        const int base_t = t0 + wave * 8 + bb * 4;   // global token of q=0
        const int base_l = wave * 8 + bb * 4;        // block-local
        int iv[4], jv[4];
#pragma unroll
        for (int q = 0; q < 4; ++q) { iv[q] = seq[base_t + q]; jv[q] = seq2[base_t + q]; }
#pragma unroll
        for (int pair = 0; pair < 2; ++pair) {
            const int qa = pair * 2, qb = pair * 2 + 1;
            const float4* GiA = (const float4*)(G + iv[qa] * Vn);
            const float4* GjA = (const float4*)(G + jv[qa] * Vn);
            const float4* GiB = (const float4*)(G + iv[qb] * Vn);
            const float4* GjB = (const float4*)(G + jv[qb] * Vn);
            float4 gia[4], gja[4], gib[4], gjb[4];
#pragma unroll
            for (int s = 0; s < 4; ++s) {
                const int e = s * 64 + lane;
                gia[s] = GiA[e];
                gja[s] = GjA[e];
                gib[s] = GiB[e];
                gjb[s] = GjB[e];
            }
            float bestA = __builtin_inff(), bestB = __builtin_inff();
            int vA = 0, vB = 0;
#pragma unroll
            for (int s = 0; s < 4; ++s) {
                const int e = s * 64 + lane;  // v = 4e..4e+3 ascending per lane
                const float4 nn = nn_r[s];
                const int v = e * 4;
                {
                    const float s0 = fmaf(c1, gja[s].x, fmaf(c0, gia[s].x, nn.x));
                    const float s1 = fmaf(c1, gja[s].y, fmaf(c0, gia[s].y, nn.y));
                    const float s2 = fmaf(c1, gja[s].z, fmaf(c0, gia[s].z, nn.z));
                    const float s3 = fmaf(c1, gja[s].w, fmaf(c0, gia[s].w, nn.w));
                    if (s0 < bestA) { bestA = s0; vA = v; }
                    if (s1 < bestA) { bestA = s1; vA = v + 1; }
                    if (s2 < bestA) { bestA = s2; vA = v + 2; }
                    if (s3 < bestA) { bestA = s3; vA = v + 3; }
                }
                {
                    const float s0 = fmaf(c1, gjb[s].x, fmaf(c0, gib[s].x, nn.x));
                    const float s1 = fmaf(c1, gjb[s].y, fmaf(c0, gib[s].y, nn.y));
                    const float s2 = fmaf(c1, gjb[s].z, fmaf(c0, gib[s].z, nn.z));
                    const float s3 = fmaf(c1, gjb[s].w, fmaf(c0, gib[s].w, nn.w));
                    if (s0 < bestB) { bestB = s0; vB = v; }
                    if (s1 < bestB) { bestB = s1; vB = v + 1; }
                    if (s2 < bestB) { bestB = s2; vB = v + 2; }
                    if (s3 < bestB) { bestB = s3; vB = v + 3; }
                }
            }
            // 64-lane reduce, lexicographic (score, v) = jnp.argmin first-min
#pragma unroll
            for (int off = 32; off >= 1; off >>= 1) {
                const float oa = __shfl_down(bestA, off, 64);
                const int   va = __shfl_down(vA, off, 64);
                if (oa < bestA || (oa == bestA && va < vA)) { bestA = oa; vA = va; }
                const float ob = __shfl_down(bestB, off, 64);
                const int   vb = __shfl_down(vB, off, 64);
                if (ob < bestB || (ob == bestB && vb < vB)) { bestB = ob; vB = vb; }
            }
            if (lane == 0) {
                bestVs[base_l + qa] = vA;
                bestVs[base_l + qb] = vB;
            }
        }
    }
    __syncthreads();

    // ---- Phase 2: two d-halves of 128; T[32][129] --------------------------
    const int b   = t0 >> 8;
    const int hw0 = t0 & 255;
    float* outb = out + b * 65536 + hw0;
    const int tok = tid >> 3;        // 0..31 (gather mapping)
    const int l8  = tid & 7;
    const int hw4  = (tid & 7) * 4;  // 0..28 (write mapping)
    const int drow = tid >> 3;       // 0..31
#pragma unroll
    for (int half = 0; half < 2; ++half) {
        // 2a: gather W rows -> T. 8 lanes/token, 128 B contiguous per token.
        const int v = bestVs[tok];
        const float4* Wr = (const float4*)(W + v * Dn + half * 128);
#pragma unroll
        for (int p = 0; p < 4; ++p) {
            const int d4 = p * 8 + l8;          // local float4 idx, 0..31
            const float4 w4 = Wr[d4];
            T[tok][d4 * 4 + 0] = w4.x;
            T[tok][d4 * 4 + 1] = w4.y;
            T[tok][d4 * 4 + 2] = w4.z;
            T[tok][d4 * 4 + 3] = w4.w;
        }
        __syncthreads();
        // 2b: transposed vfloat4 writes; each 8-lane group = one 128 B line.
#pragma unroll
        for (int dp = 0; dp < 128; dp += 32) {
            const int dl = dp + drow;           // local d, 0..127
            const int d = half * 128 + dl;
            vfloat4 o;
            o.x = T[hw4 + 0][dl];
            o.y = T[hw4 + 1][dl];
            o.z = T[hw4 + 2][dl];
            o.w = T[hw4 + 3][dl];
            __builtin_nontemporal_store(o, (vfloat4*)(outb + d * 256 + hw4));
        }
        __syncthreads();
    }
}

// ---------------------------------------------------------------------------
extern "C" void kernel_launch(void* const* d_in, const int* in_sizes, int n_in,
                              void* d_out, int out_size, void* d_ws, size_t ws_size,
                              hipStream_t stream) {
    const int*   seq   = (const int*)d_in[0];    // [256,256] int32
    const int*   seq2  = (const int*)d_in[1];    // [256,256] int32
    const float* alpha = (const float*)d_in[2];  // [1]
    const float* W     = (const float*)d_in[3];  // [1024,256] f32
    float* out = (float*)d_out;                  // [256,256,16,16] f32

    char* ws = (char*)d_ws;
    float* G     = (float*)(ws);             // 4 MB
    float* norms = (float*)(ws + 4194304);   // 4 KB

    gram_kernel<<<dim3(32, 32), 256, 0, stream>>>(W, G, norms);
    argmin_write_kernel<<<NT / 32, 256, 0, stream>>>(seq, seq2, alpha, G, norms, W, out);
}